// Round 1
// baseline (406.790 us; speedup 1.0000x reference)
//
#include <hip/hip_runtime.h>
#include <stdint.h>

#define EPS 1e-8f

constexpr int C  = 256;     // channels (K dim)
constexpr int HW = 16384;   // pixels per image (M and N dims)
constexpr int BM = 128, BN = 128, BK = 64;

typedef __attribute__((ext_vector_type(8))) short short8;
typedef __attribute__((ext_vector_type(4))) float floatx4;
typedef unsigned short u16;
typedef unsigned long long u64;

__device__ inline u16 f2bf(float x) {   // RNE float -> bf16 bits (finite inputs)
    unsigned u = __float_as_uint(x);
    unsigned r = (u + 0x7FFFu + ((u >> 16) & 1u)) >> 16;
    return (u16)r;
}

__device__ inline unsigned mapf(float f) {  // monotone float -> uint (for max)
    unsigned u = __float_as_uint(f);
    return (u & 0x80000000u) ? ~u : (u | 0x80000000u);
}

// ---------------------------------------------------------------------------
// P1: per-pixel channel sum-of-squares for a and b, plus inverse norms.
// block = 256 threads = 4 c-chunks x 64 pixels; grid = HW/64.
__global__ void norms_kernel(const float* __restrict__ a, const float* __restrict__ b,
                             float* __restrict__ sumsq_a, float* __restrict__ sumsq_b,
                             float* __restrict__ inv_na, float* __restrict__ inv_nb) {
    __shared__ float pa[4][64], pb[4][64];
    int tid = threadIdx.x;
    int tc = tid >> 6, px = tid & 63;
    int p = blockIdx.x * 64 + px;
    float sa = 0.f, sb = 0.f;
    for (int c = tc * 64; c < tc * 64 + 64; ++c) {
        float va = a[(size_t)c * HW + p]; sa += va * va;
        float vb = b[(size_t)c * HW + p]; sb += vb * vb;
    }
    pa[tc][px] = sa; pb[tc][px] = sb;
    __syncthreads();
    if (tid < 64) {
        float A = pa[0][px] + pa[1][px] + pa[2][px] + pa[3][px];
        float B = pb[0][px] + pb[1][px] + pb[2][px] + pb[3][px];
        sumsq_a[p] = A; sumsq_b[p] = B;
        inv_na[p] = 1.0f / (sqrtf(A + EPS) + EPS);   // matches ref: / (sqrt(ss+EPS)+EPS)
        inv_nb[p] = 1.0f / (sqrtf(B + EPS) + EPS);
    }
}

// ---------------------------------------------------------------------------
// P2: transpose [c][p] -> [p][c], normalize, cast to bf16.
// block (32,8), grid (HW/32, C/32).
__global__ void transpose_norm(const float* __restrict__ x, const float* __restrict__ inv_n,
                               u16* __restrict__ xT) {
    __shared__ float tile[32][33];
    int tx = threadIdx.x, ty = threadIdx.y;
    int p0 = blockIdx.x * 32, c0 = blockIdx.y * 32;
    int p = p0 + tx;
    float inv = inv_n[p];
    #pragma unroll
    for (int i = 0; i < 4; ++i) {
        int c = c0 + ty + i * 8;
        tile[ty + i * 8][tx] = x[(size_t)c * HW + p] * inv;
    }
    __syncthreads();
    #pragma unroll
    for (int i = 0; i < 4; ++i) {
        int pr = p0 + ty + i * 8;
        int cc = c0 + tx;
        xT[(size_t)pr * C + cc] = f2bf(tile[tx][ty + i * 8]);
    }
}

// ---------------------------------------------------------------------------
// G: fused GEMM (S = aT . bT^T over K=256) + per-row argmax into packed u64.
// 128x128 tile, 4 waves (2x2 of 64x64), mfma_f32_16x16x32_bf16,
// global_load_lds width-16 staging, XOR chunk swizzle (16B granule per 128B row).
__global__ __launch_bounds__(256) void gemm_argmax(const u16* __restrict__ aT,
                                                   const u16* __restrict__ bT,
                                                   u64* __restrict__ packed) {
    __shared__ union { u16 ab[2][BM * BK]; u64 cand[BM][32]; } sm;
    const int tid = threadIdx.x;
    const int w = tid >> 6, lane = tid & 63;
    const int q4 = lane >> 4, r15 = lane & 15;
    const int wm = w >> 1, wn = w & 1;
    const int p0 = blockIdx.x * BM, q0 = blockIdx.y * BN;
    const int lr = lane >> 3;   // row within 8-row staging group
    const int sc = lane & 7;    // stored 16B-chunk index

    floatx4 acc[4][4] = {};

    for (int it = 0; it < 4; ++it) {
        const int k0 = it * BK;
        // stage A tile: wave w covers rows w*32 .. w*32+31, 8 rows per instruction
        #pragma unroll
        for (int i = 0; i < 4; ++i) {
            int row = w * 32 + i * 8 + lr;
            int gc = sc ^ (row & 7);                         // global chunk for this LDS slot
            const u16* gp = aT + (size_t)(p0 + row) * C + k0 + gc * 8;
            u16* lp = &sm.ab[0][row * BK + sc * 8];          // = base + lane*16B (contiguous)
            __builtin_amdgcn_global_load_lds((const __attribute__((address_space(1))) void*)gp,
                                             (__attribute__((address_space(3))) void*)lp, 16, 0, 0);
        }
        #pragma unroll
        for (int i = 0; i < 4; ++i) {
            int row = w * 32 + i * 8 + lr;
            int gc = sc ^ (row & 7);
            const u16* gp = bT + (size_t)(q0 + row) * C + k0 + gc * 8;
            u16* lp = &sm.ab[1][row * BK + sc * 8];
            __builtin_amdgcn_global_load_lds((const __attribute__((address_space(1))) void*)gp,
                                             (__attribute__((address_space(3))) void*)lp, 16, 0, 0);
        }
        __syncthreads();   // compiler drains vmcnt before barrier

        #pragma unroll
        for (int ks = 0; ks < 2; ++ks) {
            short8 af[4], bf[4];
            #pragma unroll
            for (int mi = 0; mi < 4; ++mi) {
                int row = wm * 64 + mi * 16 + r15;
                int scc = (ks * 4 + q4) ^ (row & 7);
                af[mi] = *(const short8*)&sm.ab[0][row * BK + scc * 8];
            }
            #pragma unroll
            for (int ni = 0; ni < 4; ++ni) {
                int row = wn * 64 + ni * 16 + r15;
                int scc = (ks * 4 + q4) ^ (row & 7);
                bf[ni] = *(const short8*)&sm.ab[1][row * BK + scc * 8];
            }
            #pragma unroll
            for (int mi = 0; mi < 4; ++mi)
                #pragma unroll
                for (int ni = 0; ni < 4; ++ni)
                    acc[mi][ni] = __builtin_amdgcn_mfma_f32_16x16x32_bf16(af[mi], bf[ni], acc[mi][ni], 0, 0, 0);
        }
        __syncthreads();
    }

    // epilogue phase 1: per-lane best over ni for each of its 16 rows -> LDS
    // D layout: col = lane&15 (n), row = q4*4+reg (m) within each 16x16 tile.
    #pragma unroll
    for (int mi = 0; mi < 4; ++mi) {
        #pragma unroll
        for (int reg = 0; reg < 4; ++reg) {
            int rowl = wm * 64 + mi * 16 + q4 * 4 + reg;
            u64 best = 0;
            #pragma unroll
            for (int ni = 0; ni < 4; ++ni) {
                float v = acc[mi][ni][reg];
                unsigned qc = (unsigned)(q0 + wn * 64 + ni * 16 + r15);
                u64 pk = ((u64)mapf(v) << 32) | (u64)(0xFFFFFFFFu - qc);  // ties -> smallest q
                best = best > pk ? best : pk;
            }
            sm.cand[rowl][wn * 16 + r15] = best;
        }
    }
    __syncthreads();
    // phase 2: 2 threads per row reduce the 32 candidates, one atomic per row
    {
        int row = tid >> 1, half = tid & 1;
        u64 best = 0;
        #pragma unroll
        for (int j = 0; j < 16; ++j) {
            u64 v = sm.cand[row][half * 16 + j];
            best = best > v ? best : v;
        }
        u64 o = __shfl_xor(best, 1);
        best = best > o ? best : o;
        if (half == 0) atomicMax(&packed[p0 + row], best);
    }
}

// ---------------------------------------------------------------------------
// L: exact fp32 loss. block = 4 c-chunks x 64 pixels, grid = HW/64.
__global__ void loss_kernel(const float* __restrict__ a, const float* __restrict__ b,
                            const u64* __restrict__ packed,
                            const float* __restrict__ sumsq_a, const float* __restrict__ sumsq_b,
                            float* __restrict__ out) {
    __shared__ float part[4][64];
    int tid = threadIdx.x;
    int tc = tid >> 6, px = tid & 63;
    int p = blockIdx.x * 64 + px;
    unsigned q = 0xFFFFFFFFu - (unsigned)(packed[p] & 0xFFFFFFFFull);
    float dot = 0.f;
    for (int c = tc * 64; c < tc * 64 + 64; ++c)
        dot += a[(size_t)c * HW + p] * b[(size_t)c * HW + q];
    part[tc][px] = dot;
    __syncthreads();
    if (tid < 64) {
        float d = part[0][px] + part[1][px] + part[2][px] + part[3][px];
        float an = sqrtf(sumsq_a[p]);          // ref: no EPS inside sqrt here
        float tn = sqrtf(sumsq_b[q]);
        float cossim = d / ((an + EPS) * (tn + EPS));
        float v = (1.0f - cossim) * (1.0f / (float)HW);
        #pragma unroll
        for (int m = 1; m < 64; m <<= 1) v += __shfl_xor(v, m);
        if (tid == 0) atomicAdd(out, v);
    }
}

// ---------------------------------------------------------------------------
extern "C" void kernel_launch(void* const* d_in, const int* in_sizes, int n_in,
                              void* d_out, int out_size, void* d_ws, size_t ws_size,
                              hipStream_t stream) {
    const float* a = (const float*)d_in[0];
    const float* b = (const float*)d_in[1];
    float* out = (float*)d_out;
    char* ws = (char*)d_ws;

    u16*   aT      = (u16*)ws;                                   // 8 MB
    u16*   bT      = (u16*)(ws + (size_t)8 * 1024 * 1024);       // 8 MB
    float* sumsq_a = (float*)(ws + (size_t)16 * 1024 * 1024);    // 64 KB
    float* sumsq_b = sumsq_a + HW;
    float* inv_na  = sumsq_b + HW;
    float* inv_nb  = inv_na + HW;
    u64*   packed  = (u64*)(inv_nb + HW);                        // 128 KB

    hipMemsetAsync(out, 0, sizeof(float), stream);
    hipMemsetAsync(packed, 0, (size_t)HW * sizeof(u64), stream);

    norms_kernel<<<dim3(HW / 64), 256, 0, stream>>>(a, b, sumsq_a, sumsq_b, inv_na, inv_nb);
    transpose_norm<<<dim3(HW / 32, C / 32), dim3(32, 8), 0, stream>>>(a, inv_na, aT);
    transpose_norm<<<dim3(HW / 32, C / 32), dim3(32, 8), 0, stream>>>(b, inv_nb, bT);
    gemm_argmax<<<dim3(HW / BM, HW / BN), 256, 0, stream>>>(aT, bT, packed);
    loss_kernel<<<dim3(HW / 64), 256, 0, stream>>>(a, b, packed, sumsq_a, sumsq_b, out);
}

// Round 2
// 366.538 us; speedup vs baseline: 1.1098x; 1.1098x over previous
//
#include <hip/hip_runtime.h>
#include <stdint.h>

#define EPS 1e-8f

constexpr int C  = 256;     // channels (K dim)
constexpr int HW = 16384;   // pixels per image (M and N dims)
constexpr int BM = 128, BN = 128, BK = 64;

typedef __attribute__((ext_vector_type(8))) short short8;
typedef __attribute__((ext_vector_type(4))) float floatx4;
typedef unsigned short u16;
typedef unsigned int u32;
typedef unsigned long long u64;

__device__ inline u16 f2bf(float x) {   // RNE float -> bf16 bits (finite inputs)
    unsigned u = __float_as_uint(x);
    unsigned r = (u + 0x7FFFu + ((u >> 16) & 1u)) >> 16;
    return (u16)r;
}

__device__ inline unsigned mapf(float f) {  // monotone float -> uint (for max)
    unsigned u = __float_as_uint(f);
    return (u & 0x80000000u) ? ~u : (u | 0x80000000u);
}

#define GLD16(gp, lp) __builtin_amdgcn_global_load_lds( \
    (const __attribute__((address_space(1))) void*)(gp), \
    (__attribute__((address_space(3))) void*)(lp), 16, 0, 0)

// ---------------------------------------------------------------------------
// P1: per-pixel channel sum-of-squares for a and b, plus inverse norms.
__global__ void norms_kernel(const float* __restrict__ a, const float* __restrict__ b,
                             float* __restrict__ sumsq_a, float* __restrict__ sumsq_b,
                             float* __restrict__ inv_na, float* __restrict__ inv_nb) {
    __shared__ float pa[4][64], pb[4][64];
    int tid = threadIdx.x;
    int tc = tid >> 6, px = tid & 63;
    int p = blockIdx.x * 64 + px;
    float sa = 0.f, sb = 0.f;
    for (int c = tc * 64; c < tc * 64 + 64; ++c) {
        float va = a[(size_t)c * HW + p]; sa += va * va;
        float vb = b[(size_t)c * HW + p]; sb += vb * vb;
    }
    pa[tc][px] = sa; pb[tc][px] = sb;
    __syncthreads();
    if (tid < 64) {
        float A = pa[0][px] + pa[1][px] + pa[2][px] + pa[3][px];
        float B = pb[0][px] + pb[1][px] + pb[2][px] + pb[3][px];
        sumsq_a[p] = A; sumsq_b[p] = B;
        inv_na[p] = 1.0f / (sqrtf(A + EPS) + EPS);
        inv_nb[p] = 1.0f / (sqrtf(B + EPS) + EPS);
    }
}

// ---------------------------------------------------------------------------
// P2: transpose [c][p] -> [p][c], normalize, cast to bf16.
__global__ void transpose_norm(const float* __restrict__ x, const float* __restrict__ inv_n,
                               u16* __restrict__ xT) {
    __shared__ float tile[32][33];
    int tx = threadIdx.x, ty = threadIdx.y;
    int p0 = blockIdx.x * 32, c0 = blockIdx.y * 32;
    int p = p0 + tx;
    float inv = inv_n[p];
    #pragma unroll
    for (int i = 0; i < 4; ++i) {
        int c = c0 + ty + i * 8;
        tile[ty + i * 8][tx] = x[(size_t)c * HW + p] * inv;
    }
    __syncthreads();
    #pragma unroll
    for (int i = 0; i < 4; ++i) {
        int pr = p0 + ty + i * 8;
        int cc = c0 + tx;
        xT[(size_t)pr * C + cc] = f2bf(tile[tx][ty + i * 8]);
    }
}

// ---------------------------------------------------------------------------
// G: fused GEMM (S = aT . bT^T over K=256) + per-row argmax into packed u64.
// LDS holds 32 slabs of 1KB in MFMA *fragment order*: lane l's 16B of slab
// (wm,mi,ks) is A[row = wm*64+mi*16+(l&15)][kchunk = ks*4+(l>>4)].
// Staging gathers on the GLOBAL side (per-lane addresses); LDS side is the
// required uniform_base + lane*16. Fragment ds_read_b128 = lane-consecutive
// => conflict-free.
__global__ __launch_bounds__(256) void gemm_argmax(const u16* __restrict__ aT,
                                                   const u16* __restrict__ bT,
                                                   u64* __restrict__ packed) {
    __shared__ union { u16 ab[32 * 512]; u64 cand[BM][32]; } sm;   // 32 KB
    const int tid = threadIdx.x;
    const int w = tid >> 6, lane = tid & 63;
    const int q4 = lane >> 4, r15 = lane & 15;
    const int wm = w >> 1, wn = w & 1;
    const int p0 = blockIdx.x * BM, q0 = blockIdx.y * BN;

    u16* ldsA = sm.ab;              // slabs 0..15  : A (wm*8 + mi*2 + ks)
    u16* ldsB = sm.ab + 16 * 512;   // slabs 0..15  : B (wn*8 + ni*2 + ks)

    // wave w stages A slabs w*4+i and B slabs w*4+i (i=0..3), 8 instrs/iter.
    // slab s: tile-row = (s>>3)*64 + ((s>>1)&3)*16 + (l&15);
    //         tile-col(u16) = (s&1)*32 + (l>>4)*8
    u32 offA[4], offB[4];
    #pragma unroll
    for (int i = 0; i < 4; ++i) {
        int s = w * 4 + i;
        int rowt = (s >> 3) * 64 + ((s >> 1) & 3) * 16 + r15;
        int colt = (s & 1) * 32 + q4 * 8;
        offA[i] = (u32)(p0 + rowt) * C + colt;
        offB[i] = (u32)(q0 + rowt) * C + colt;
    }

    floatx4 acc[4][4] = {};

    for (int it = 0; it < 4; ++it) {
        const int k0 = it * BK;
        #pragma unroll
        for (int i = 0; i < 4; ++i) {
            int s = w * 4 + i;
            GLD16(aT + offA[i] + k0, ldsA + s * 512 + lane * 8);
            GLD16(bT + offB[i] + k0, ldsB + s * 512 + lane * 8);
        }
        __syncthreads();   // compiler drains vmcnt before barrier

        #pragma unroll
        for (int ks = 0; ks < 2; ++ks) {
            short8 af[4], bf[4];
            #pragma unroll
            for (int mi = 0; mi < 4; ++mi)
                af[mi] = *(const short8*)&ldsA[(wm * 8 + mi * 2 + ks) * 512 + lane * 8];
            #pragma unroll
            for (int ni = 0; ni < 4; ++ni)
                bf[ni] = *(const short8*)&ldsB[(wn * 8 + ni * 2 + ks) * 512 + lane * 8];
            #pragma unroll
            for (int mi = 0; mi < 4; ++mi)
                #pragma unroll
                for (int ni = 0; ni < 4; ++ni)
                    acc[mi][ni] = __builtin_amdgcn_mfma_f32_16x16x32_bf16(af[mi], bf[ni], acc[mi][ni], 0, 0, 0);
        }
        __syncthreads();
    }

    // epilogue phase 1: per-lane best over ni for each of its 16 rows -> LDS
    // D layout: col = lane&15 (n), row = q4*4+reg (m) within each 16x16 tile.
    #pragma unroll
    for (int mi = 0; mi < 4; ++mi) {
        #pragma unroll
        for (int reg = 0; reg < 4; ++reg) {
            int rowl = wm * 64 + mi * 16 + q4 * 4 + reg;
            u64 best = 0;
            #pragma unroll
            for (int ni = 0; ni < 4; ++ni) {
                float v = acc[mi][ni][reg];
                unsigned qc = (unsigned)(q0 + wn * 64 + ni * 16 + r15);
                u64 pk = ((u64)mapf(v) << 32) | (u64)(0xFFFFFFFFu - qc);  // ties -> smallest q
                best = best > pk ? best : pk;
            }
            sm.cand[rowl][wn * 16 + r15] = best;
        }
    }
    __syncthreads();
    // phase 2: 2 threads per row reduce the 32 candidates (diagonal-staggered
    // columns to spread banks), one atomic per row.
    {
        int row = tid >> 1, half = tid & 1;
        u64 best = 0;
        #pragma unroll
        for (int j = 0; j < 16; ++j) {
            int col = half * 16 + ((j + row) & 15);
            u64 v = sm.cand[row][col];
            best = best > v ? best : v;
        }
        u64 o = __shfl_xor(best, 1);
        best = best > o ? best : o;
        if (half == 0) atomicMax(&packed[p0 + row], best);
    }
}

// ---------------------------------------------------------------------------
// L: exact fp32 loss. block = 4 c-chunks x 64 pixels, grid = HW/64.
__global__ void loss_kernel(const float* __restrict__ a, const float* __restrict__ b,
                            const u64* __restrict__ packed,
                            const float* __restrict__ sumsq_a, const float* __restrict__ sumsq_b,
                            float* __restrict__ out) {
    __shared__ float part[4][64];
    int tid = threadIdx.x;
    int tc = tid >> 6, px = tid & 63;
    int p = blockIdx.x * 64 + px;
    unsigned q = 0xFFFFFFFFu - (unsigned)(packed[p] & 0xFFFFFFFFull);
    float dot = 0.f;
    for (int c = tc * 64; c < tc * 64 + 64; ++c)
        dot += a[(size_t)c * HW + p] * b[(size_t)c * HW + q];
    part[tc][px] = dot;
    __syncthreads();
    if (tid < 64) {
        float d = part[0][px] + part[1][px] + part[2][px] + part[3][px];
        float an = sqrtf(sumsq_a[p]);
        float tn = sqrtf(sumsq_b[q]);
        float cossim = d / ((an + EPS) * (tn + EPS));
        float v = (1.0f - cossim) * (1.0f / (float)HW);
        #pragma unroll
        for (int m = 1; m < 64; m <<= 1) v += __shfl_xor(v, m);
        if (tid == 0) atomicAdd(out, v);
    }
}

// ---------------------------------------------------------------------------
extern "C" void kernel_launch(void* const* d_in, const int* in_sizes, int n_in,
                              void* d_out, int out_size, void* d_ws, size_t ws_size,
                              hipStream_t stream) {
    const float* a = (const float*)d_in[0];
    const float* b = (const float*)d_in[1];
    float* out = (float*)d_out;
    char* ws = (char*)d_ws;

    u16*   aT      = (u16*)ws;                                   // 8 MB
    u16*   bT      = (u16*)(ws + (size_t)8 * 1024 * 1024);       // 8 MB
    float* sumsq_a = (float*)(ws + (size_t)16 * 1024 * 1024);    // 64 KB
    float* sumsq_b = sumsq_a + HW;
    float* inv_na  = sumsq_b + HW;
    float* inv_nb  = inv_na + HW;
    u64*   packed  = (u64*)(inv_nb + HW);                        // 128 KB

    hipMemsetAsync(out, 0, sizeof(float), stream);
    hipMemsetAsync(packed, 0, (size_t)HW * sizeof(u64), stream);

    norms_kernel<<<dim3(HW / 64), 256, 0, stream>>>(a, b, sumsq_a, sumsq_b, inv_na, inv_nb);
    transpose_norm<<<dim3(HW / 32, C / 32), dim3(32, 8), 0, stream>>>(a, inv_na, aT);
    transpose_norm<<<dim3(HW / 32, C / 32), dim3(32, 8), 0, stream>>>(b, inv_nb, bT);
    gemm_argmax<<<dim3(HW / BM, HW / BN), 256, 0, stream>>>(aT, bT, packed);
    loss_kernel<<<dim3(HW / 64), 256, 0, stream>>>(a, b, packed, sumsq_a, sumsq_b, out);
}